// Round 1
// baseline (231.651 us; speedup 1.0000x reference)
//
#include <hip/hip_runtime.h>
#include <hip/hip_bf16.h>
#include <math.h>

#define NB 32768
#define DD 128
#define HH 512
#define EE 16
#define TM 64

typedef __attribute__((ext_vector_type(8))) short short8;
typedef __attribute__((ext_vector_type(4))) float f32x4;

__device__ __forceinline__ unsigned short f2bf(float f) {
  union { float f; unsigned u; } v; v.f = f;
  unsigned r = v.u + 0x7fffu + ((v.u >> 16) & 1u);
  return (unsigned short)(r >> 16);
}

// ---------------- weight transpose + bf16 cast ----------------
// w1 (E,D,H) fp32 -> w1T (E,H,D) bf16 ; w2 (E,H,D) fp32 -> w2T (E,D,H) bf16
__global__ __launch_bounds__(256) void transpose_kernel(
    const float* __restrict__ w1, const float* __restrict__ w2,
    unsigned short* __restrict__ w1T, unsigned short* __restrict__ w2T) {
  __shared__ float tile[32][33];
  int b = blockIdx.x;
  int tx = threadIdx.x & 31, ty = threadIdx.x >> 5;
  if (b < 1024) {
    int e = b >> 6, t = b & 63;
    int d0 = (t >> 4) * 32, h0 = (t & 15) * 32;
    const float* src = w1 + (size_t)e * DD * HH;
    #pragma unroll
    for (int j = 0; j < 4; ++j)
      tile[ty + j * 8][tx] = src[(size_t)(d0 + ty + j * 8) * HH + h0 + tx];
    __syncthreads();
    unsigned short* dst = w1T + (size_t)e * HH * DD;
    #pragma unroll
    for (int j = 0; j < 4; ++j)
      dst[(size_t)(h0 + ty + j * 8) * DD + d0 + tx] = f2bf(tile[tx][ty + j * 8]);
  } else {
    int bb = b - 1024;
    int e = bb >> 6, t = bb & 63;
    int h0 = (t >> 2) * 32, d0 = (t & 3) * 32;
    const float* src = w2 + (size_t)e * HH * DD;
    #pragma unroll
    for (int j = 0; j < 4; ++j)
      tile[ty + j * 8][tx] = src[(size_t)(h0 + ty + j * 8) * DD + d0 + tx];
    __syncthreads();
    unsigned short* dst = w2T + (size_t)e * DD * HH;
    #pragma unroll
    for (int j = 0; j < 4; ++j)
      dst[(size_t)(d0 + ty + j * 8) * HH + h0 + tx] = f2bf(tile[tx][ty + j * 8]);
  }
}

// ---------------- gating: fp64 logits, argmax, bucket scatter ----------------
__global__ __launch_bounds__(256) void gate_kernel(
    const float* __restrict__ x, const float* __restrict__ wg,
    const float* __restrict__ bg, int* __restrict__ counts,
    int* __restrict__ rows) {
  int b = blockIdx.x * 256 + threadIdx.x;
  double acc[EE];
  #pragma unroll
  for (int e = 0; e < EE; ++e) acc[e] = (double)bg[e];
  const float4* xr = (const float4*)(x + (size_t)b * DD);
  #pragma unroll 4
  for (int d4 = 0; d4 < DD / 4; ++d4) {
    float4 v = xr[d4];
    float xv[4] = {v.x, v.y, v.z, v.w};
    #pragma unroll
    for (int i = 0; i < 4; ++i) {
      int dd = d4 * 4 + i;
      #pragma unroll
      for (int e = 0; e < EE; ++e)
        acc[e] += (double)xv[i] * (double)wg[dd * EE + e];  // wg uniform -> s_load
    }
  }
  int beste = 0; double bestv = acc[0];
  #pragma unroll
  for (int e = 1; e < EE; ++e)
    if (acc[e] > bestv) { bestv = acc[e]; beste = e; }  // strict > keeps lowest idx (top_k tie rule)
  int pos = atomicAdd(&counts[beste], 1);
  rows[beste * NB + pos] = b;
}

// ---------------- grouped expert GEMM: out[r] = gelu(x[r]@w1[e]) @ w2[e] ----------------
__global__ __launch_bounds__(256) void moe_gemm(
    const float* __restrict__ x, const unsigned short* __restrict__ w1T,
    const unsigned short* __restrict__ w2T, const int* __restrict__ counts,
    const int* __restrict__ rows, float* __restrict__ out) {
  int e = blockIdx.y;
  int cnt = counts[e];
  int base = blockIdx.x * TM;
  if (base >= cnt) return;

  // +8 bf16 pad per row -> row stride 272B/144B: 16B-aligned, 2-way bank alias only (free)
  __shared__ unsigned short sX[TM][136];   // gathered x rows, bf16, [m][d]
  __shared__ unsigned short sW1[64][136];  // w1T chunk [h_local][d]  (B1: k=d contiguous)
  __shared__ unsigned short sW2[DD][72];   // w2T chunk [d][h_local]  (B2: k=h contiguous)
  __shared__ unsigned short sH[TM][72];    // hidden chunk [m][h_local]

  int tid = threadIdx.x;
  // stage gathered X rows (fp32 -> bf16); 4 threads per row, 32 cols each
  {
    int m = tid >> 2;
    int c0 = (tid & 3) * 32;
    int ridx = base + m; if (ridx >= cnt) ridx = cnt - 1;  // clamp: padded rows masked at store
    int grow = rows[e * NB + ridx];
    const float4* src = (const float4*)(x + (size_t)grow * DD + c0);
    #pragma unroll
    for (int i = 0; i < 8; ++i) {
      float4 v = src[i];
      ushort4 p;
      p.x = f2bf(v.x); p.y = f2bf(v.y); p.z = f2bf(v.z); p.w = f2bf(v.w);
      *(ushort4*)&sX[m][c0 + i * 4] = p;
    }
  }

  int wv = tid >> 6;   // wave id: owns rows [wv*16, wv*16+16)
  int l  = tid & 63;
  int lm = l & 15;     // A: m / B: n / C: col
  int q  = l >> 4;
  int k0 = q * 8;      // A/B fragment k-offset

  f32x4 acc2[8];       // persistent out accumulator: 16 rows x 128 cols
  #pragma unroll
  for (int n = 0; n < 8; ++n) acc2[n] = (f32x4){0.f, 0.f, 0.f, 0.f};

  for (int hc = 0; hc < HH / 64; ++hc) {
    int h0 = hc * 64;
    // stage w1T chunk: rows h0..h0+63 x 128d = contiguous 16KB in global
    {
      const uint4* src = (const uint4*)(w1T + ((size_t)e * HH + h0) * DD);
      #pragma unroll
      for (int i = 0; i < 4; ++i) {
        int u = tid + i * 256;
        int r = u >> 4, c = u & 15;
        *(uint4*)&sW1[r][c * 8] = src[u];
      }
    }
    // stage w2T chunk: 128 rows x 64 cols (h0..h0+63)
    {
      #pragma unroll
      for (int i = 0; i < 4; ++i) {
        int u = tid + i * 256;
        int r = u >> 3, c = u & 7;
        const uint4* src = (const uint4*)(w2T + ((size_t)e * DD + r) * HH + h0);
        *(uint4*)&sW2[r][c * 8] = src[c];
      }
    }
    __syncthreads();

    // GEMM1: hidden(16x64 per wave) = Xg(16x128) @ W1chunk(128x64)
    f32x4 acc1[4];
    #pragma unroll
    for (int n = 0; n < 4; ++n) acc1[n] = (f32x4){0.f, 0.f, 0.f, 0.f};
    #pragma unroll
    for (int ks = 0; ks < 4; ++ks) {
      int kk = ks * 32 + k0;
      short8 a = *(const short8*)&sX[wv * 16 + lm][kk];
      #pragma unroll
      for (int n = 0; n < 4; ++n) {
        short8 bfr = *(const short8*)&sW1[n * 16 + lm][kk];
        acc1[n] = __builtin_amdgcn_mfma_f32_16x16x32_bf16(a, bfr, acc1[n], 0, 0, 0);
      }
    }
    // exact gelu, cast bf16, into sH (C layout: row=q*4+r, col=lm)
    #pragma unroll
    for (int n = 0; n < 4; ++n) {
      #pragma unroll
      for (int r = 0; r < 4; ++r) {
        float v = acc1[n][r];
        float g = 0.5f * v * (1.0f + erff(v * 0.70710678118654752f));
        sH[wv * 16 + q * 4 + r][n * 16 + lm] = f2bf(g);
      }
    }
    __syncthreads();

    // GEMM2 partial: out(16x128 per wave) += H(16x64) @ W2chunk(64x128)
    #pragma unroll
    for (int ks = 0; ks < 2; ++ks) {
      int kk = ks * 32 + k0;
      short8 a = *(const short8*)&sH[wv * 16 + lm][kk];
      #pragma unroll
      for (int n = 0; n < 8; ++n) {
        short8 bfr = *(const short8*)&sW2[n * 16 + lm][kk];
        acc2[n] = __builtin_amdgcn_mfma_f32_16x16x32_bf16(a, bfr, acc2[n], 0, 0, 0);
      }
    }
    __syncthreads();  // protect sW1/sW2/sH before next chunk's staging
  }

  // epilogue: scatter rows (score == 1.0 for top-1 softmax)
  #pragma unroll
  for (int r = 0; r < 4; ++r) {
    int ml = wv * 16 + q * 4 + r;
    int ridx = base + ml;
    if (ridx < cnt) {
      int grow = rows[e * NB + ridx];
      float* op = out + (size_t)grow * DD + lm;
      #pragma unroll
      for (int n = 0; n < 8; ++n) op[n * 16] = acc2[n][r];
    }
  }
}

extern "C" void kernel_launch(void* const* d_in, const int* in_sizes, int n_in,
                              void* d_out, int out_size, void* d_ws, size_t ws_size,
                              hipStream_t stream) {
  const float* x  = (const float*)d_in[0];
  const float* w1 = (const float*)d_in[1];
  const float* w2 = (const float*)d_in[2];
  const float* wg = (const float*)d_in[3];
  const float* bg = (const float*)d_in[4];
  float* out = (float*)d_out;

  // workspace layout (needs ~6.3 MB):
  // [0,64)        counts[16]
  // [1024, +2MB)  rows[16][32768]
  // then w1T bf16 (E,H,D) 2MB ; w2T bf16 (E,D,H) 2MB
  int* counts = (int*)d_ws;
  int* rows   = (int*)((char*)d_ws + 1024);
  unsigned short* w1T = (unsigned short*)((char*)d_ws + 1024 + (size_t)EE * NB * 4);
  unsigned short* w2T = w1T + (size_t)EE * HH * DD;

  hipMemsetAsync(d_ws, 0, 64, stream);
  hipLaunchKernelGGL(transpose_kernel, dim3(2048), dim3(256), 0, stream, w1, w2, w1T, w2T);
  hipLaunchKernelGGL(gate_kernel, dim3(NB / 256), dim3(256), 0, stream, x, wg, bg, counts, rows);
  hipLaunchKernelGGL(moe_gemm, dim3(NB / TM, EE), dim3(256), 0, stream, x, w1T, w2T, counts, rows, out);
}

// Round 2
// 227.994 us; speedup vs baseline: 1.0160x; 1.0160x over previous
//
#include <hip/hip_runtime.h>
#include <hip/hip_bf16.h>
#include <math.h>

#define NB 32768
#define DD 128
#define HH 512
#define EE 16
#define TM 64

typedef __attribute__((ext_vector_type(8))) short short8;
typedef __attribute__((ext_vector_type(4))) float f32x4;

__device__ __forceinline__ unsigned short f2bf(float f) {
  union { float f; unsigned u; } v; v.f = f;
  unsigned r = v.u + 0x7fffu + ((v.u >> 16) & 1u);
  return (unsigned short)(r >> 16);
}

// ---------------- weight transpose + bf16 cast ----------------
// w1 (E,D,H) fp32 -> w1T (E,H,D) bf16 ; w2 (E,H,D) fp32 -> w2T (E,D,H) bf16
__global__ __launch_bounds__(256) void transpose_kernel(
    const float* __restrict__ w1, const float* __restrict__ w2,
    unsigned short* __restrict__ w1T, unsigned short* __restrict__ w2T) {
  __shared__ float tile[32][33];
  int b = blockIdx.x;
  int tx = threadIdx.x & 31, ty = threadIdx.x >> 5;
  if (b < 1024) {
    int e = b >> 6, t = b & 63;
    int d0 = (t >> 4) * 32, h0 = (t & 15) * 32;
    const float* src = w1 + (size_t)e * DD * HH;
    #pragma unroll
    for (int j = 0; j < 4; ++j)
      tile[ty + j * 8][tx] = src[(size_t)(d0 + ty + j * 8) * HH + h0 + tx];
    __syncthreads();
    unsigned short* dst = w1T + (size_t)e * HH * DD;
    #pragma unroll
    for (int j = 0; j < 4; ++j)
      dst[(size_t)(h0 + ty + j * 8) * DD + d0 + tx] = f2bf(tile[tx][ty + j * 8]);
  } else {
    int bb = b - 1024;
    int e = bb >> 6, t = bb & 63;
    int h0 = (t >> 2) * 32, d0 = (t & 3) * 32;
    const float* src = w2 + (size_t)e * HH * DD;
    #pragma unroll
    for (int j = 0; j < 4; ++j)
      tile[ty + j * 8][tx] = src[(size_t)(h0 + ty + j * 8) * DD + d0 + tx];
    __syncthreads();
    unsigned short* dst = w2T + (size_t)e * DD * HH;
    #pragma unroll
    for (int j = 0; j < 4; ++j)
      dst[(size_t)(d0 + ty + j * 8) * HH + h0 + tx] = f2bf(tile[tx][ty + j * 8]);
  }
}

// ---------------- gating: LDS-staged, fp64 accumulate, 4 acc/thread ----------------
// block = 256 threads handles 64 rows; thread t: row = t>>2, experts (t&3)*4..+4
__global__ __launch_bounds__(256) void gate_kernel(
    const float* __restrict__ x, const float* __restrict__ wg,
    const float* __restrict__ bg, int* __restrict__ counts,
    int* __restrict__ rows) {
  __shared__ float sx[64][132];    // 33.8 KB; stride 132 -> 2-way bank alias (free)
  __shared__ double swg[DD][EE];   // 16 KB, cvt once per block

  int tid = threadIdx.x;
  int base = blockIdx.x * 64;

  // stage wg as fp64 (coalesced read, 8 elems/thread)
  for (int i = tid; i < DD * EE; i += 256) swg[i >> 4][i & 15] = (double)wg[i];
  // stage x rows fp32: 4 threads/row, 32 cols each (8x float4)
  {
    int r = tid >> 2, c0 = (tid & 3) * 32;
    const float4* src = (const float4*)(x + (size_t)(base + r) * DD + c0);
    #pragma unroll
    for (int i = 0; i < 8; ++i)
      *(float4*)&sx[r][c0 + i * 4] = src[i];
  }
  __syncthreads();

  int r = tid >> 2;
  int e0 = (tid & 3) * 4;
  double acc[4];
  #pragma unroll
  for (int j = 0; j < 4; ++j) acc[j] = (double)bg[e0 + j];

  #pragma unroll 4
  for (int d = 0; d < DD; ++d) {
    double xv = (double)sx[r][d];
    #pragma unroll
    for (int j = 0; j < 4; ++j)
      acc[j] += xv * swg[d][e0 + j];
  }

  // thread-local argmax (strict > keeps lowest idx, matching top_k tie rule)
  int beste = 0; double bestv = acc[0];
  #pragma unroll
  for (int j = 1; j < 4; ++j)
    if (acc[j] > bestv) { bestv = acc[j]; beste = j; }
  int ge = e0 + beste;

  // reduce across the 4 consecutive lanes owning this row
  #pragma unroll
  for (int off = 1; off < 4; off <<= 1) {
    double ov = __shfl_xor(bestv, off);
    int oe = __shfl_xor(ge, off);
    if (ov > bestv || (ov == bestv && oe < ge)) { bestv = ov; ge = oe; }
  }

  if ((tid & 3) == 0) {
    int pos = atomicAdd(&counts[ge], 1);
    rows[ge * NB + pos] = base + r;
  }
}

// ---------------- grouped expert GEMM: out[r] = gelu(x[r]@w1[e]) @ w2[e] ----------------
__global__ __launch_bounds__(256) void moe_gemm(
    const float* __restrict__ x, const unsigned short* __restrict__ w1T,
    const unsigned short* __restrict__ w2T, const int* __restrict__ counts,
    const int* __restrict__ rows, float* __restrict__ out) {
  int e = blockIdx.y;
  int cnt = counts[e];
  int base = blockIdx.x * TM;
  if (base >= cnt) return;

  // +8 bf16 pad per row -> row stride 272B/144B: 16B-aligned, 2-way bank alias only (free)
  __shared__ unsigned short sX[TM][136];   // gathered x rows, bf16, [m][d]
  __shared__ unsigned short sW1[64][136];  // w1T chunk [h_local][d]  (B1: k=d contiguous)
  __shared__ unsigned short sW2[DD][72];   // w2T chunk [d][h_local]  (B2: k=h contiguous)
  __shared__ unsigned short sH[TM][72];    // hidden chunk [m][h_local]

  int tid = threadIdx.x;
  // stage gathered X rows (fp32 -> bf16); 4 threads per row, 32 cols each
  {
    int m = tid >> 2;
    int c0 = (tid & 3) * 32;
    int ridx = base + m; if (ridx >= cnt) ridx = cnt - 1;  // clamp: padded rows masked at store
    int grow = rows[e * NB + ridx];
    const float4* src = (const float4*)(x + (size_t)grow * DD + c0);
    #pragma unroll
    for (int i = 0; i < 8; ++i) {
      float4 v = src[i];
      ushort4 p;
      p.x = f2bf(v.x); p.y = f2bf(v.y); p.z = f2bf(v.z); p.w = f2bf(v.w);
      *(ushort4*)&sX[m][c0 + i * 4] = p;
    }
  }

  int wv = tid >> 6;   // wave id: owns rows [wv*16, wv*16+16)
  int l  = tid & 63;
  int lm = l & 15;     // A: m / B: n / C: col
  int q  = l >> 4;
  int k0 = q * 8;      // A/B fragment k-offset

  f32x4 acc2[8];       // persistent out accumulator: 16 rows x 128 cols
  #pragma unroll
  for (int n = 0; n < 8; ++n) acc2[n] = (f32x4){0.f, 0.f, 0.f, 0.f};

  for (int hc = 0; hc < HH / 64; ++hc) {
    int h0 = hc * 64;
    // stage w1T chunk: rows h0..h0+63 x 128d = contiguous 16KB in global
    {
      const uint4* src = (const uint4*)(w1T + ((size_t)e * HH + h0) * DD);
      #pragma unroll
      for (int i = 0; i < 4; ++i) {
        int u = tid + i * 256;
        int r = u >> 4, c = u & 15;
        *(uint4*)&sW1[r][c * 8] = src[u];
      }
    }
    // stage w2T chunk: 128 rows x 64 cols (h0..h0+63)
    {
      #pragma unroll
      for (int i = 0; i < 4; ++i) {
        int u = tid + i * 256;
        int r = u >> 3, c = u & 7;
        const uint4* src = (const uint4*)(w2T + ((size_t)e * DD + r) * HH + h0);
        *(uint4*)&sW2[r][c * 8] = src[c];
      }
    }
    __syncthreads();

    // GEMM1: hidden(16x64 per wave) = Xg(16x128) @ W1chunk(128x64)
    f32x4 acc1[4];
    #pragma unroll
    for (int n = 0; n < 4; ++n) acc1[n] = (f32x4){0.f, 0.f, 0.f, 0.f};
    #pragma unroll
    for (int ks = 0; ks < 4; ++ks) {
      int kk = ks * 32 + k0;
      short8 a = *(const short8*)&sX[wv * 16 + lm][kk];
      #pragma unroll
      for (int n = 0; n < 4; ++n) {
        short8 bfr = *(const short8*)&sW1[n * 16 + lm][kk];
        acc1[n] = __builtin_amdgcn_mfma_f32_16x16x32_bf16(a, bfr, acc1[n], 0, 0, 0);
      }
    }
    // exact gelu, cast bf16, into sH (C layout: row=q*4+r, col=lm)
    #pragma unroll
    for (int n = 0; n < 4; ++n) {
      #pragma unroll
      for (int r = 0; r < 4; ++r) {
        float v = acc1[n][r];
        float g = 0.5f * v * (1.0f + erff(v * 0.70710678118654752f));
        sH[wv * 16 + q * 4 + r][n * 16 + lm] = f2bf(g);
      }
    }
    __syncthreads();

    // GEMM2 partial: out(16x128 per wave) += H(16x64) @ W2chunk(64x128)
    #pragma unroll
    for (int ks = 0; ks < 2; ++ks) {
      int kk = ks * 32 + k0;
      short8 a = *(const short8*)&sH[wv * 16 + lm][kk];
      #pragma unroll
      for (int n = 0; n < 8; ++n) {
        short8 bfr = *(const short8*)&sW2[n * 16 + lm][kk];
        acc2[n] = __builtin_amdgcn_mfma_f32_16x16x32_bf16(a, bfr, acc2[n], 0, 0, 0);
      }
    }
    __syncthreads();  // protect sW1/sW2/sH before next chunk's staging
  }

  // epilogue: scatter rows (score == 1.0 for top-1 softmax)
  #pragma unroll
  for (int r = 0; r < 4; ++r) {
    int ml = wv * 16 + q * 4 + r;
    int ridx = base + ml;
    if (ridx < cnt) {
      int grow = rows[e * NB + ridx];
      float* op = out + (size_t)grow * DD + lm;
      #pragma unroll
      for (int n = 0; n < 8; ++n) op[n * 16] = acc2[n][r];
    }
  }
}

extern "C" void kernel_launch(void* const* d_in, const int* in_sizes, int n_in,
                              void* d_out, int out_size, void* d_ws, size_t ws_size,
                              hipStream_t stream) {
  const float* x  = (const float*)d_in[0];
  const float* w1 = (const float*)d_in[1];
  const float* w2 = (const float*)d_in[2];
  const float* wg = (const float*)d_in[3];
  const float* bg = (const float*)d_in[4];
  float* out = (float*)d_out;

  // workspace layout (needs ~6.3 MB):
  // [0,64)        counts[16]
  // [1024, +2MB)  rows[16][32768]
  // then w1T bf16 (E,H,D) 2MB ; w2T bf16 (E,D,H) 2MB
  int* counts = (int*)d_ws;
  int* rows   = (int*)((char*)d_ws + 1024);
  unsigned short* w1T = (unsigned short*)((char*)d_ws + 1024 + (size_t)EE * NB * 4);
  unsigned short* w2T = w1T + (size_t)EE * HH * DD;

  hipMemsetAsync(d_ws, 0, 64, stream);
  hipLaunchKernelGGL(transpose_kernel, dim3(2048), dim3(256), 0, stream, w1, w2, w1T, w2T);
  hipLaunchKernelGGL(gate_kernel, dim3(NB / 64), dim3(256), 0, stream, x, wg, bg, counts, rows);
  hipLaunchKernelGGL(moe_gemm, dim3(NB / TM, EE), dim3(256), 0, stream, x, w1T, w2T, counts, rows, out);
}

// Round 3
// 142.830 us; speedup vs baseline: 1.6219x; 1.5963x over previous
//
#include <hip/hip_runtime.h>
#include <hip/hip_bf16.h>
#include <math.h>

#define NB 32768
#define DD 128
#define HH 512
#define EE 16
#define TM 64

typedef __attribute__((ext_vector_type(8))) short short8;
typedef __attribute__((ext_vector_type(4))) float f32x4;

__device__ __forceinline__ unsigned short f2bf(float f) {
  union { float f; unsigned u; } v; v.f = f;
  unsigned r = v.u + 0x7fffu + ((v.u >> 16) & 1u);
  return (unsigned short)(r >> 16);
}

// Abramowitz-Stegun 7.1.26 erf, |eps| <= 1.5e-7 (far below bf16 noise)
__device__ __forceinline__ float fast_erf(float z) {
  float a = fabsf(z);
  float t = 1.0f / (1.0f + 0.3275911f * a);
  float y = t * (0.254829592f + t * (-0.284496736f + t * (1.421413741f +
            t * (-1.453152027f + t * 1.061405429f))));
  float r = 1.0f - y * __expf(-a * a);
  return z < 0.0f ? -r : r;
}

// ---------------- weight transpose + bf16 cast ----------------
// w1 (E,D,H) fp32 -> w1T (E,H,D) bf16 ; w2 (E,H,D) fp32 -> w2T (E,D,H) bf16
__global__ __launch_bounds__(256) void transpose_kernel(
    const float* __restrict__ w1, const float* __restrict__ w2,
    unsigned short* __restrict__ w1T, unsigned short* __restrict__ w2T) {
  __shared__ float tile[32][33];
  int b = blockIdx.x;
  int tx = threadIdx.x & 31, ty = threadIdx.x >> 5;
  if (b < 1024) {
    int e = b >> 6, t = b & 63;
    int d0 = (t >> 4) * 32, h0 = (t & 15) * 32;
    const float* src = w1 + (size_t)e * DD * HH;
    #pragma unroll
    for (int j = 0; j < 4; ++j)
      tile[ty + j * 8][tx] = src[(size_t)(d0 + ty + j * 8) * HH + h0 + tx];
    __syncthreads();
    unsigned short* dst = w1T + (size_t)e * HH * DD;
    #pragma unroll
    for (int j = 0; j < 4; ++j)
      dst[(size_t)(h0 + ty + j * 8) * DD + d0 + tx] = f2bf(tile[tx][ty + j * 8]);
  } else {
    int bb = b - 1024;
    int e = bb >> 6, t = bb & 63;
    int h0 = (t >> 2) * 32, d0 = (t & 3) * 32;
    const float* src = w2 + (size_t)e * HH * DD;
    #pragma unroll
    for (int j = 0; j < 4; ++j)
      tile[ty + j * 8][tx] = src[(size_t)(h0 + ty + j * 8) * DD + d0 + tx];
    __syncthreads();
    unsigned short* dst = w2T + (size_t)e * DD * HH;
    #pragma unroll
    for (int j = 0; j < 4; ++j)
      dst[(size_t)(d0 + ty + j * 8) * HH + h0 + tx] = f2bf(tile[tx][ty + j * 8]);
  }
}

// ---------------- gating: fp64 logits + block-aggregated bucket scatter ----------------
// block = 256 threads handles 64 rows; thread t: row = t>>2, experts (t&3)*4..+4
// Global atomic traffic: 16 adds/block (range reservation), not 64.
__global__ __launch_bounds__(256) void gate_kernel(
    const float* __restrict__ x, const float* __restrict__ wg,
    const float* __restrict__ bg, int* __restrict__ counts,
    int* __restrict__ rows) {
  __shared__ float sx[64][132];    // stride 132 -> 2-way bank alias (free)
  __shared__ double swg[DD][EE];
  __shared__ int lcnt[EE];         // block-local histogram
  __shared__ int gbase[EE];        // reserved global base per expert
  __shared__ int lslot[64];        // per-row local slot
  __shared__ int lexp[64];         // per-row chosen expert

  int tid = threadIdx.x;
  int base = blockIdx.x * 64;

  if (tid < EE) lcnt[tid] = 0;
  // stage wg as fp64 (coalesced read)
  for (int i = tid; i < DD * EE; i += 256) swg[i >> 4][i & 15] = (double)wg[i];
  // stage x rows fp32: 4 threads/row, 32 cols each
  {
    int r = tid >> 2, c0 = (tid & 3) * 32;
    const float4* src = (const float4*)(x + (size_t)(base + r) * DD + c0);
    #pragma unroll
    for (int i = 0; i < 8; ++i)
      *(float4*)&sx[r][c0 + i * 4] = src[i];
  }
  __syncthreads();

  int r = tid >> 2;
  int e0 = (tid & 3) * 4;
  double acc[4];
  #pragma unroll
  for (int j = 0; j < 4; ++j) acc[j] = (double)bg[e0 + j];

  #pragma unroll 4
  for (int d = 0; d < DD; ++d) {
    double xv = (double)sx[r][d];
    #pragma unroll
    for (int j = 0; j < 4; ++j)
      acc[j] += xv * swg[d][e0 + j];
  }

  // thread-local argmax (strict > keeps lowest idx, matching top_k tie rule)
  int beste = 0; double bestv = acc[0];
  #pragma unroll
  for (int j = 1; j < 4; ++j)
    if (acc[j] > bestv) { bestv = acc[j]; beste = j; }
  int ge = e0 + beste;

  // reduce across the 4 consecutive lanes owning this row
  #pragma unroll
  for (int off = 1; off < 4; off <<= 1) {
    double ov = __shfl_xor(bestv, off);
    int oe = __shfl_xor(ge, off);
    if (ov > bestv || (ov == bestv && oe < ge)) { bestv = ov; ge = oe; }
  }

  if ((tid & 3) == 0) {
    lslot[r] = atomicAdd(&lcnt[ge], 1);   // LDS atomic: cheap
    lexp[r] = ge;
  }
  __syncthreads();
  if (tid < EE && lcnt[tid] > 0)
    gbase[tid] = atomicAdd(&counts[tid], lcnt[tid]);  // 16 global atomics/block
  __syncthreads();
  if ((tid & 3) == 0) {
    int e2 = lexp[r];
    rows[e2 * NB + gbase[e2] + lslot[r]] = base + r;
  }
}

// ---------------- grouped expert GEMM: out[r] = gelu(x[r]@w1[e]) @ w2[e] ----------------
__global__ __launch_bounds__(256) void moe_gemm(
    const float* __restrict__ x, const unsigned short* __restrict__ w1T,
    const unsigned short* __restrict__ w2T, const int* __restrict__ counts,
    const int* __restrict__ rows, float* __restrict__ out) {
  int e = blockIdx.y;
  int cnt = counts[e];
  int base = blockIdx.x * TM;
  if (base >= cnt) return;

  // +8 bf16 pad per row -> row stride 272B/144B: 16B-aligned, 2-way bank alias only (free)
  __shared__ unsigned short sX[TM][136];   // gathered x rows, bf16, [m][d]
  __shared__ unsigned short sW1[64][136];  // w1T chunk [h_local][d]  (B1: k=d contiguous)
  __shared__ unsigned short sW2[DD][72];   // w2T chunk [d][h_local]  (B2: k=h contiguous)
  __shared__ unsigned short sH[TM][72];    // hidden chunk [m][h_local]

  int tid = threadIdx.x;
  // stage gathered X rows (fp32 -> bf16); 4 threads per row, 32 cols each
  {
    int m = tid >> 2;
    int c0 = (tid & 3) * 32;
    int ridx = base + m; if (ridx >= cnt) ridx = cnt - 1;  // clamp: padded rows masked at store
    int grow = rows[e * NB + ridx];
    const float4* src = (const float4*)(x + (size_t)grow * DD + c0);
    #pragma unroll
    for (int i = 0; i < 8; ++i) {
      float4 v = src[i];
      ushort4 p;
      p.x = f2bf(v.x); p.y = f2bf(v.y); p.z = f2bf(v.z); p.w = f2bf(v.w);
      *(ushort4*)&sX[m][c0 + i * 4] = p;
    }
  }

  int wv = tid >> 6;   // wave id: owns rows [wv*16, wv*16+16)
  int l  = tid & 63;
  int lm = l & 15;     // A: m / B: n / C: col
  int q  = l >> 4;
  int k0 = q * 8;      // A/B fragment k-offset

  f32x4 acc2[8];       // persistent out accumulator: 16 rows x 128 cols
  #pragma unroll
  for (int n = 0; n < 8; ++n) acc2[n] = (f32x4){0.f, 0.f, 0.f, 0.f};

  for (int hc = 0; hc < HH / 64; ++hc) {
    int h0 = hc * 64;
    // stage w1T chunk: rows h0..h0+63 x 128d = contiguous 16KB in global
    {
      const uint4* src = (const uint4*)(w1T + ((size_t)e * HH + h0) * DD);
      #pragma unroll
      for (int i = 0; i < 4; ++i) {
        int u = tid + i * 256;
        int r = u >> 4, c = u & 15;
        *(uint4*)&sW1[r][c * 8] = src[u];
      }
    }
    // stage w2T chunk: 128 rows x 64 cols (h0..h0+63)
    {
      #pragma unroll
      for (int i = 0; i < 4; ++i) {
        int u = tid + i * 256;
        int r = u >> 3, c = u & 7;
        const uint4* src = (const uint4*)(w2T + ((size_t)e * DD + r) * HH + h0);
        *(uint4*)&sW2[r][c * 8] = src[c];
      }
    }
    __syncthreads();

    // GEMM1: hidden(16x64 per wave) = Xg(16x128) @ W1chunk(128x64)
    f32x4 acc1[4];
    #pragma unroll
    for (int n = 0; n < 4; ++n) acc1[n] = (f32x4){0.f, 0.f, 0.f, 0.f};
    #pragma unroll
    for (int ks = 0; ks < 4; ++ks) {
      int kk = ks * 32 + k0;
      short8 a = *(const short8*)&sX[wv * 16 + lm][kk];
      #pragma unroll
      for (int n = 0; n < 4; ++n) {
        short8 bfr = *(const short8*)&sW1[n * 16 + lm][kk];
        acc1[n] = __builtin_amdgcn_mfma_f32_16x16x32_bf16(a, bfr, acc1[n], 0, 0, 0);
      }
    }
    // exact-to-1.5e-7 gelu, cast bf16, into sH (C layout: row=q*4+r, col=lm)
    #pragma unroll
    for (int n = 0; n < 4; ++n) {
      #pragma unroll
      for (int r = 0; r < 4; ++r) {
        float v = acc1[n][r];
        float g = 0.5f * v * (1.0f + fast_erf(v * 0.70710678118654752f));
        sH[wv * 16 + q * 4 + r][n * 16 + lm] = f2bf(g);
      }
    }
    __syncthreads();

    // GEMM2 partial: out(16x128 per wave) += H(16x64) @ W2chunk(64x128)
    #pragma unroll
    for (int ks = 0; ks < 2; ++ks) {
      int kk = ks * 32 + k0;
      short8 a = *(const short8*)&sH[wv * 16 + lm][kk];
      #pragma unroll
      for (int n = 0; n < 8; ++n) {
        short8 bfr = *(const short8*)&sW2[n * 16 + lm][kk];
        acc2[n] = __builtin_amdgcn_mfma_f32_16x16x32_bf16(a, bfr, acc2[n], 0, 0, 0);
      }
    }
    __syncthreads();  // protect sW1/sW2/sH before next chunk's staging
  }

  // epilogue: scatter rows (score == 1.0 for top-1 softmax)
  #pragma unroll
  for (int r = 0; r < 4; ++r) {
    int ml = wv * 16 + q * 4 + r;
    int ridx = base + ml;
    if (ridx < cnt) {
      int grow = rows[e * NB + ridx];
      float* op = out + (size_t)grow * DD + lm;
      #pragma unroll
      for (int n = 0; n < 8; ++n) op[n * 16] = acc2[n][r];
    }
  }
}

extern "C" void kernel_launch(void* const* d_in, const int* in_sizes, int n_in,
                              void* d_out, int out_size, void* d_ws, size_t ws_size,
                              hipStream_t stream) {
  const float* x  = (const float*)d_in[0];
  const float* w1 = (const float*)d_in[1];
  const float* w2 = (const float*)d_in[2];
  const float* wg = (const float*)d_in[3];
  const float* bg = (const float*)d_in[4];
  float* out = (float*)d_out;

  // workspace layout (needs ~6.3 MB):
  // [0,64)        counts[16]
  // [1024, +2MB)  rows[16][32768]
  // then w1T bf16 (E,H,D) 2MB ; w2T bf16 (E,D,H) 2MB
  int* counts = (int*)d_ws;
  int* rows   = (int*)((char*)d_ws + 1024);
  unsigned short* w1T = (unsigned short*)((char*)d_ws + 1024 + (size_t)EE * NB * 4);
  unsigned short* w2T = w1T + (size_t)EE * HH * DD;

  hipMemsetAsync(d_ws, 0, 64, stream);
  hipLaunchKernelGGL(transpose_kernel, dim3(2048), dim3(256), 0, stream, w1, w2, w1T, w2T);
  hipLaunchKernelGGL(gate_kernel, dim3(NB / 64), dim3(256), 0, stream, x, wg, bg, counts, rows);
  hipLaunchKernelGGL(moe_gemm, dim3(NB / TM, EE), dim3(256), 0, stream, x, w1T, w2T, counts, rows, out);
}